// Round 16
// baseline (81.870 us; speedup 1.0000x reference)
//
#include <hip/hip_runtime.h>
#include <hip/hip_bf16.h>

#define DB 8
#define DT 2048
#define DC 1024
#define DH 128

typedef __attribute__((ext_vector_type(8))) short short8;
typedef __attribute__((ext_vector_type(4))) float f32x4;
typedef __attribute__((ext_vector_type(4))) int i32x4;
typedef __attribute__((ext_vector_type(4))) unsigned short u16x4;

// round-to-nearest-even f32 -> bf16 bits
static __device__ __forceinline__ unsigned short bfbits(float x){
    union { float f; unsigned u; } a; a.f = x;
    unsigned u = a.u;
    unsigned r = u + 0x7fffu + ((u >> 16) & 1u);
    return (unsigned short)(r >> 16);
}
static __device__ __forceinline__ unsigned pbf2(float lo, float hi){
    return (unsigned)bfbits(lo) | ((unsigned)bfbits(hi) << 16);
}
static __device__ __forceinline__ float bf2f(unsigned short u){
    union { unsigned u; float f; } t; t.u = ((unsigned)u) << 16; return t.f;
}

// async 16B global -> LDS (direct, no VGPR round-trip)
static __device__ __forceinline__ void gload16(const void* g, void* l){
    __builtin_amdgcn_global_load_lds(
        (const __attribute__((address_space(1))) unsigned int*)g,
        (__attribute__((address_space(3))) unsigned int*)l, 16, 0, 0);
}

// Redistribute 32 kv-wide P slice into PV B-fragment layout. Verified R0..R15.
static __device__ __forceinline__ short8 redist(unsigned pk0, unsigned pk1,
                                                unsigned pk2, unsigned pk3,
                                                int g, int c){
    const int src0 = c + (((2*g    ) & 3) << 4);
    const int src1 = c + (((2*g + 1) & 3) << 4);
    const int sel  = g >> 1;
    unsigned a0 = __shfl(pk0, src0), a2 = __shfl(pk2, src0);
    unsigned b0 = __shfl(pk1, src0), b2 = __shfl(pk3, src0);
    unsigned c0 = __shfl(pk0, src1), c2 = __shfl(pk2, src1);
    unsigned d0 = __shfl(pk1, src1), d2 = __shfl(pk3, src1);
    i32x4 pw = { (int)(sel ? a2 : a0), (int)(sel ? b2 : b0),
                 (int)(sel ? c2 : c0), (int)(sel ? d2 : d0) };
    return __builtin_bit_cast(short8, pw);
}

// WTc[t][chunk][n][e] = W_p[k][h] bf16 (unchanged).
__global__ __launch_bounds__(256) void prep_wt_kernel(const float* __restrict__ Wq,
                                                      const float* __restrict__ Wk,
                                                      const float* __restrict__ Wv,
                                                      unsigned short* __restrict__ WTc){
    int gid = blockIdx.x * 256 + threadIdx.x;
    int e  = gid & 7;
    int F3 = gid >> 3;
    int n  = F3 % 384;
    int ct = F3 / 384;
    int k  = (ct >> 2) * 32 + (ct & 3) * 8 + e;
    int p  = n >> 7, h = n & 127;
    const float* W = (p == 0) ? Wq : (p == 1 ? Wk : Wv);
    float v = W[(size_t)k * DH + h];
    if (p == 0) v *= 0.08838834764831845f * 1.4426950408889634f;
    WTc[gid] = bfbits(v);
}

// Fused QKV projection v5 (R14 passing version, best measured total):
// BM=64, BK=64, grid 256 (1 block/CU), B via global_load_lds, A reg-staged.
__global__ __launch_bounds__(512, 2) void qkv_kernel(const float* __restrict__ x,
                                                     const unsigned short* __restrict__ WTc,
                                                     unsigned short* __restrict__ Qb,
                                                     unsigned short* __restrict__ Kb,
                                                     unsigned short* __restrict__ VT){
    __shared__ unsigned short Bs[2][24576];   // 2 x 48KB
    __shared__ unsigned short As[2][4608];    // 2 x 9KB (64 rows x stride 72)

    const int tid  = threadIdx.x;
    const int lane = tid & 63;
    const int w    = tid >> 6;
    const int g = lane >> 4, c = lane & 15;
    const int m0 = blockIdx.x * 64;
    const int n0 = w * 48;

    const unsigned short* bsrc = WTc + (size_t)tid * 8;
    const int arow = tid >> 3, ac8 = tid & 7;
    const float* asrc = x + (size_t)(m0 + arow) * DC + ac8 * 8;

    f32x4 acc[4][3] = {};
    float4 av0, av1;

#pragma unroll
    for (int j = 0; j < 6; ++j)
        gload16(bsrc + j * 4096, &Bs[0][j * 4096 + tid * 8]);
    {
        av0 = *(const float4*)asrc; av1 = *(const float4*)(asrc + 4);
        i32x4 h8 = { (int)pbf2(av0.x, av0.y), (int)pbf2(av0.z, av0.w),
                     (int)pbf2(av1.x, av1.y), (int)pbf2(av1.z, av1.w) };
        *(i32x4*)(&As[0][arow * 72 + ac8 * 8]) = h8;
    }

    for (int t = 0; t < DC / 64; ++t){
        const int cur = t & 1;
        __syncthreads();
        if (t < DC / 64 - 1){
#pragma unroll
            for (int j = 0; j < 6; ++j)
                gload16(bsrc + (t + 1) * 24576 + j * 4096,
                        &Bs[cur ^ 1][j * 4096 + tid * 8]);
            av0 = *(const float4*)(asrc + (t + 1) * 64);
            av1 = *(const float4*)(asrc + (t + 1) * 64 + 4);
        }
#pragma unroll
        for (int kk = 0; kk < 2; ++kk){
            short8 af[4], bfr[3];
#pragma unroll
            for (int mf = 0; mf < 4; ++mf)
                af[mf] = *(const short8*)(&As[cur][(mf*16 + c) * 72 + kk*32 + g * 8]);
#pragma unroll
            for (int nf = 0; nf < 3; ++nf)
                bfr[nf] = *(const short8*)(&Bs[cur][kk*12288 + g * 3072 + (n0 + nf*16 + c) * 8]);
#pragma unroll
            for (int mf = 0; mf < 4; ++mf)
#pragma unroll
                for (int nf = 0; nf < 3; ++nf)
                    acc[mf][nf] = __builtin_amdgcn_mfma_f32_16x16x32_bf16(af[mf], bfr[nf], acc[mf][nf], 0, 0, 0);
        }
        if (t < DC / 64 - 1){
            i32x4 h8 = { (int)pbf2(av0.x, av0.y), (int)pbf2(av0.z, av0.w),
                         (int)pbf2(av1.x, av1.y), (int)pbf2(av1.z, av1.w) };
            *(i32x4*)(&As[cur ^ 1][arow * 72 + ac8 * 8]) = h8;
        }
    }

    const int bb = m0 >> 11;
    const int tb = m0 & 2047;
#pragma unroll
    for (int mf = 0; mf < 4; ++mf)
#pragma unroll
        for (int nf = 0; nf < 3; ++nf){
            const int n  = n0 + nf*16;
            const int p  = n >> 7;
            const int np = (n & 127) + c;
            const int row = m0 + mf*16 + 4*g;
            if (p < 2){
                unsigned short* O = (p == 0) ? Qb : Kb;
#pragma unroll
                for (int r = 0; r < 4; ++r)
                    O[(size_t)(row + r) * DH + np] = bfbits(acc[mf][nf][r]);
            } else {
                const int t0 = tb + mf*16 + 4*g;
                u16x4 v = { bfbits(acc[mf][nf][0]), bfbits(acc[mf][nf][1]),
                            bfbits(acc[mf][nf][2]), bfbits(acc[mf][nf][3]) };
                *(u16x4*)(VT + ((size_t)bb * DH + np) * DT + t0) = v;
            }
        }
}

// Causal flash attention v8: 128 q-rows/block (4 waves x 32 rows as two 16-row
// subtiles sharing kf/vf LDS reads -> half the LDS traffic per MFMA),
// kv-split-4, grid 8x16x4=512 (2 blocks/CU). Sync skeleton identical to the
// R12-R15 proven version. Wave-uniform predicate skips tiles above a wave's
// diagonal (kv0 <= base0 guarantees no all-masked lane).
__global__ __launch_bounds__(256, 2) void attn_kernel(const unsigned short* __restrict__ Qb,
                                                      const unsigned short* __restrict__ Kb,
                                                      const unsigned short* __restrict__ VT,
                                                      unsigned short* __restrict__ OP,
                                                      float* __restrict__ ML){
    __shared__ unsigned char lds[2][32768];   // per buf: K 16KB @0, V 16KB @16384

    const int tid  = threadIdx.x;
    const int lane = tid & 63;
    const int w    = tid >> 6;
    const int g = lane >> 4, c = lane & 15;
    const int bi = blockIdx.x;
    const int b  = bi & 7;
    const int idx = bi >> 3;               // 0..63
    const int qt  = idx & 15;              // 128-row q-tile
    const int s   = idx >> 4;              // kv quarter 0..3
    const int base0 = qt * 128 + w * 32;   // wave's first q row
    const int q0v = base0 + c;             // subtile 0 rows
    const int q1v = base0 + 16 + c;        // subtile 1 rows
    const int nt  = 2 * (qt + 1);          // kv tiles (KVBLK=64) for this q-tile
    const int kt0 = (nt * s) >> 2;
    const int kt1 = (nt * (s + 1)) >> 2;

    const unsigned short* Kbase = Kb + (size_t)b * DT * DH;
    const unsigned short* Vbase = VT + (size_t)b * DH * DT;

    short8 qf0[4], qf1[4];
#pragma unroll
    for (int hc = 0; hc < 4; ++hc){
        qf0[hc] = *(const short8*)(Qb + ((size_t)b*DT + base0 + c) * DH + hc*32 + g*8);
        qf1[hc] = *(const short8*)(Qb + ((size_t)b*DT + base0 + 16 + c) * DH + hc*32 + g*8);
    }

    f32x4 acc0[8] = {}, acc1[8] = {};
    float m0 = -1e30f, l0 = 0.f, m1 = -1e30f, l1 = 0.f;

    if (kt0 < kt1){
        // ---- prologue: stage first tile into buf 0 ----
        {
            const int kv0 = kt0 * 64;
#pragma unroll
            for (int p = 0; p < 4; ++p){
                const int sfl = p*256 + tid;
                const int r = sfl >> 4, cbl = (sfl & 15) * 16;
                const int h = sfl >> 3, tbl = (sfl & 7) * 16;
                gload16(Kbase + (size_t)(kv0 + r) * DH + ((cbl ^ ((r & 7) << 4)) >> 1),
                        lds[0] + sfl*16);
                gload16(Vbase + (size_t)h * DT + kv0 + ((tbl ^ ((h & 7) << 4)) >> 1),
                        lds[0] + 16384 + sfl*16);
            }
        }

        for (int kt = kt0; kt < kt1; ++kt){
            const int cur = (kt - kt0) & 1;
            const int kv0c = kt * 64;
            __syncthreads();                      // buf[cur] staged (vmcnt drained)

            // ---- issue next tile direct-to-LDS (buf[cur^1]) ----
            if (kt + 1 < kt1){
                const int nv0 = kv0c + 64;
#pragma unroll
                for (int p = 0; p < 4; ++p){
                    const int sfl = p*256 + tid;
                    const int r = sfl >> 4, cbl = (sfl & 15) * 16;
                    const int h = sfl >> 3, tbl = (sfl & 7) * 16;
                    gload16(Kbase + (size_t)(nv0 + r) * DH + ((cbl ^ ((r & 7) << 4)) >> 1),
                            lds[cur ^ 1] + sfl*16);
                    gload16(Vbase + (size_t)h * DT + nv0 + ((tbl ^ ((h & 7) << 4)) >> 1),
                            lds[cur ^ 1] + 16384 + sfl*16);
                }
            }

            // ---- wave-uniform compute predicate: tile at/below diagonal ----
            if (kv0c <= base0){
                const unsigned char* kb = lds[cur];
                const unsigned char* vb = lds[cur] + 16384;

                // ---- QK^T for both subtiles from shared kf reads ----
                f32x4 s40[4] = {}, s41[4] = {};
                short8 kf[4][4];
#pragma unroll
                for (int j = 0; j < 4; ++j){
                    const int r = 16*j + c;
#pragma unroll
                    for (int hc = 0; hc < 4; ++hc)
                        kf[j][hc] = *(const short8*)(kb + r*256 + ((hc*64 + g*16) ^ ((r & 7) << 4)));
                }
                __builtin_amdgcn_s_setprio(1);
#pragma unroll
                for (int hc = 0; hc < 4; ++hc)
#pragma unroll
                    for (int j = 0; j < 4; ++j){
                        s40[j] = __builtin_amdgcn_mfma_f32_16x16x32_bf16(kf[j][hc], qf0[hc], s40[j], 0,0,0);
                        s41[j] = __builtin_amdgcn_mfma_f32_16x16x32_bf16(kf[j][hc], qf1[hc], s41[j], 0,0,0);
                    }
                __builtin_amdgcn_s_setprio(0);

                // ---- causal mask ----
                if (kv0c + 63 > base0){
#pragma unroll
                    for (int j = 0; j < 4; ++j){
                        const int o = kv0c + 16*j + 4*g;
#pragma unroll
                        for (int r = 0; r < 4; ++r){
                            if (o + r > q0v) s40[j][r] = -1e30f;
                            if (o + r > q1v) s41[j][r] = -1e30f;
                        }
                    }
                }

                // ---- online softmax with defer-max, subtile 0 ----
                float tm0 = -1e30f, tm1 = -1e30f;
#pragma unroll
                for (int j = 0; j < 4; ++j)
#pragma unroll
                    for (int r = 0; r < 4; ++r){
                        tm0 = fmaxf(tm0, s40[j][r]);
                        tm1 = fmaxf(tm1, s41[j][r]);
                    }
                tm0 = fmaxf(tm0, __shfl_xor(tm0, 16));
                tm0 = fmaxf(tm0, __shfl_xor(tm0, 32));
                tm1 = fmaxf(tm1, __shfl_xor(tm1, 16));
                tm1 = fmaxf(tm1, __shfl_xor(tm1, 32));
                if (!__all(tm0 <= m0 + 8.f)){
                    const float mn = fmaxf(m0, tm0);
                    const float rs = exp2f(m0 - mn);
                    l0 *= rs;
#pragma unroll
                    for (int mt = 0; mt < 8; ++mt) acc0[mt] *= rs;
                    m0 = mn;
                }
                if (!__all(tm1 <= m1 + 8.f)){
                    const float mn = fmaxf(m1, tm1);
                    const float rs = exp2f(m1 - mn);
                    l1 *= rs;
#pragma unroll
                    for (int mt = 0; mt < 8; ++mt) acc1[mt] *= rs;
                    m1 = mn;
                }
                float p0[4][4], p1[4][4]; float ps0 = 0.f, ps1 = 0.f;
#pragma unroll
                for (int j = 0; j < 4; ++j)
#pragma unroll
                    for (int r = 0; r < 4; ++r){
                        p0[j][r] = exp2f(s40[j][r] - m0); ps0 += p0[j][r];
                        p1[j][r] = exp2f(s41[j][r] - m1); ps1 += p1[j][r];
                    }
                ps0 += __shfl_xor(ps0, 16); ps0 += __shfl_xor(ps0, 32); l0 += ps0;
                ps1 += __shfl_xor(ps1, 16); ps1 += __shfl_xor(ps1, 32); l1 += ps1;

                // ---- P -> B-fragment layout (2 subtiles x 2 halves) ----
                short8 pf0a = redist(pbf2(p0[0][0], p0[0][1]), pbf2(p0[0][2], p0[0][3]),
                                     pbf2(p0[1][0], p0[1][1]), pbf2(p0[1][2], p0[1][3]), g, c);
                short8 pf0b = redist(pbf2(p0[2][0], p0[2][1]), pbf2(p0[2][2], p0[2][3]),
                                     pbf2(p0[3][0], p0[3][1]), pbf2(p0[3][2], p0[3][3]), g, c);
                short8 pf1a = redist(pbf2(p1[0][0], p1[0][1]), pbf2(p1[0][2], p1[0][3]),
                                     pbf2(p1[1][0], p1[1][1]), pbf2(p1[1][2], p1[1][3]), g, c);
                short8 pf1b = redist(pbf2(p1[2][0], p1[2][1]), pbf2(p1[2][2], p1[2][3]),
                                     pbf2(p1[3][0], p1[3][1]), pbf2(p1[3][2], p1[3][3]), g, c);

                // ---- PV for both subtiles from shared vf reads ----
#pragma unroll
                for (int kk = 0; kk < 2; ++kk){
                    short8 vf[8];
#pragma unroll
                    for (int mt = 0; mt < 8; ++mt){
                        const int h = mt*16 + c;
                        vf[mt] = *(const short8*)(vb + h*128 + ((kk*64 + g*16) ^ ((h & 7) << 4)));
                    }
                    const short8 pfa = kk ? pf0b : pf0a;
                    const short8 pfb = kk ? pf1b : pf1a;
                    __builtin_amdgcn_s_setprio(1);
#pragma unroll
                    for (int mt = 0; mt < 8; ++mt){
                        acc0[mt] = __builtin_amdgcn_mfma_f32_16x16x32_bf16(vf[mt], pfa, acc0[mt], 0,0,0);
                        acc1[mt] = __builtin_amdgcn_mfma_f32_16x16x32_bf16(vf[mt], pfb, acc1[mt], 0,0,0);
                    }
                    __builtin_amdgcn_s_setprio(0);
                }
            }
        }
    }

    // ---- store partials (bf16 O, f32 m/l) for both subtiles ----
    const size_t blk = (size_t)((b * 16 + qt) * 4 + s);
    unsigned short* op = OP + blk * 16384;         // [128][128]
    const int row0 = w*32 + c;
    const int row1 = row0 + 16;
#pragma unroll
    for (int mt = 0; mt < 8; ++mt){
        u16x4 h0 = { bfbits(acc0[mt][0]), bfbits(acc0[mt][1]),
                     bfbits(acc0[mt][2]), bfbits(acc0[mt][3]) };
        u16x4 h1 = { bfbits(acc1[mt][0]), bfbits(acc1[mt][1]),
                     bfbits(acc1[mt][2]), bfbits(acc1[mt][3]) };
        *(u16x4*)(op + row0*128 + mt*16 + 4*g) = h0;
        *(u16x4*)(op + row1*128 + mt*16 + 4*g) = h1;
    }
    if (g == 0){
        ML[(blk*128 + row0)*2    ] = m0;
        ML[(blk*128 + row0)*2 + 1] = l0;
        ML[(blk*128 + row1)*2    ] = m1;
        ML[(blk*128 + row1)*2 + 1] = l1;
    }
}

// 4-way merge. Grid 256 = (b, qt, colhalf), 256 threads: r = tid>>1 (128 rows),
// 32 cols per thread.
__global__ __launch_bounds__(256) void merge_kernel(const unsigned short* __restrict__ OP,
                                                    const float* __restrict__ ML,
                                                    float* __restrict__ out){
    const int tid = threadIdx.x;
    const int r  = tid >> 1;
    const int bi = blockIdx.x;
    const int b  = bi & 7;
    const int qt = (bi >> 3) & 15;
    const int ch = (bi >> 7) * 64 + (tid & 1) * 32;
    const size_t blk = (size_t)(b * 16 + qt) * 4;

    float ms[4], ls[4];
#pragma unroll
    for (int s = 0; s < 4; ++s){
        ms[s] = ML[((blk + s)*128 + r)*2    ];
        ls[s] = ML[((blk + s)*128 + r)*2 + 1];
    }
    float M = fmaxf(fmaxf(ms[0], ms[1]), fmaxf(ms[2], ms[3]));
    float sc[4]; float L = 0.f;
#pragma unroll
    for (int s = 0; s < 4; ++s){ sc[s] = exp2f(ms[s] - M); L += ls[s] * sc[s]; }
    const float inv = 1.0f / L;

    float* orow = out + ((size_t)(b * DT + qt*128 + r)) * DH + ch;
#pragma unroll
    for (int j = 0; j < 4; ++j){
        float o[8] = {};
#pragma unroll
        for (int s = 0; s < 4; ++s){
            short8 v = *(const short8*)(OP + (blk + s)*16384 + r*128 + ch + j*8);
#pragma unroll
            for (int e = 0; e < 8; ++e)
                o[e] += bf2f((unsigned short)v[e]) * sc[s];
        }
        f32x4 o0 = { o[0]*inv, o[1]*inv, o[2]*inv, o[3]*inv };
        f32x4 o1 = { o[4]*inv, o[5]*inv, o[6]*inv, o[7]*inv };
        *(f32x4*)(orow + j*8    ) = o0;
        *(f32x4*)(orow + j*8 + 4) = o1;
    }
}

extern "C" void kernel_launch(void* const* d_in, const int* in_sizes, int n_in,
                              void* d_out, int out_size, void* d_ws, size_t ws_size,
                              hipStream_t stream){
    const float* x  = (const float*)d_in[0];
    const float* Wq = (const float*)d_in[1];
    const float* Wk = (const float*)d_in[2];
    const float* Wv = (const float*)d_in[3];
    float* out = (float*)d_out;

    unsigned short* WTc = (unsigned short*)d_ws;         // [32][4][384][8] bf16
    unsigned short* Qb = WTc + 3 * DH * DC;              // [B*T][H]
    unsigned short* Kb = Qb + (size_t)DB * DT * DH;      // [B*T][H]
    unsigned short* VT = Kb + (size_t)DB * DT * DH;      // [B][H][T]
    unsigned short* OP = VT + (size_t)DB * DT * DH;      // [512][128][128] bf16
    float*          ML = (float*)(OP + (size_t)512 * 16384); // [512][128][2] f32

    hipLaunchKernelGGL(prep_wt_kernel, dim3(1536), dim3(256), 0, stream, Wq, Wk, Wv, WTc);
    hipLaunchKernelGGL(qkv_kernel, dim3(256), dim3(512), 0, stream, x, WTc, Qb, Kb, VT);
    hipLaunchKernelGGL(attn_kernel, dim3(512), dim3(256), 0, stream, Qb, Kb, VT, OP, ML);
    hipLaunchKernelGGL(merge_kernel, dim3(256), dim3(256), 0, stream, OP, ML, out);
}

// Round 17
// 74.161 us; speedup vs baseline: 1.1039x; 1.1039x over previous
//
#include <hip/hip_runtime.h>
#include <hip/hip_bf16.h>

#define DB 8
#define DT 2048
#define DC 1024
#define DH 128

typedef __attribute__((ext_vector_type(8))) short short8;
typedef __attribute__((ext_vector_type(4))) float f32x4;
typedef __attribute__((ext_vector_type(4))) int i32x4;
typedef __attribute__((ext_vector_type(4))) unsigned short u16x4;

// round-to-nearest-even f32 -> bf16 bits
static __device__ __forceinline__ unsigned short bfbits(float x){
    union { float f; unsigned u; } a; a.f = x;
    unsigned u = a.u;
    unsigned r = u + 0x7fffu + ((u >> 16) & 1u);
    return (unsigned short)(r >> 16);
}
static __device__ __forceinline__ unsigned pbf2(float lo, float hi){
    return (unsigned)bfbits(lo) | ((unsigned)bfbits(hi) << 16);
}
static __device__ __forceinline__ float bf2f(unsigned short u){
    union { unsigned u; float f; } t; t.u = ((unsigned)u) << 16; return t.f;
}

// async 16B global -> LDS (direct, no VGPR round-trip)
static __device__ __forceinline__ void gload16(const void* g, void* l){
    __builtin_amdgcn_global_load_lds(
        (const __attribute__((address_space(1))) unsigned int*)g,
        (__attribute__((address_space(3))) unsigned int*)l, 16, 0, 0);
}

// Redistribute 32 kv-wide P slice into PV B-fragment layout. Verified R0..R16.
static __device__ __forceinline__ short8 redist(unsigned pk0, unsigned pk1,
                                                unsigned pk2, unsigned pk3,
                                                int g, int c){
    const int src0 = c + (((2*g    ) & 3) << 4);
    const int src1 = c + (((2*g + 1) & 3) << 4);
    const int sel  = g >> 1;
    unsigned a0 = __shfl(pk0, src0), a2 = __shfl(pk2, src0);
    unsigned b0 = __shfl(pk1, src0), b2 = __shfl(pk3, src0);
    unsigned c0 = __shfl(pk0, src1), c2 = __shfl(pk2, src1);
    unsigned d0 = __shfl(pk1, src1), d2 = __shfl(pk3, src1);
    i32x4 pw = { (int)(sel ? a2 : a0), (int)(sel ? b2 : b0),
                 (int)(sel ? c2 : c0), (int)(sel ? d2 : d0) };
    return __builtin_bit_cast(short8, pw);
}

// WTc[t][chunk][n][e] = W_p[k][h] bf16 (unchanged).
__global__ __launch_bounds__(256) void prep_wt_kernel(const float* __restrict__ Wq,
                                                      const float* __restrict__ Wk,
                                                      const float* __restrict__ Wv,
                                                      unsigned short* __restrict__ WTc){
    int gid = blockIdx.x * 256 + threadIdx.x;
    int e  = gid & 7;
    int F3 = gid >> 3;
    int n  = F3 % 384;
    int ct = F3 / 384;
    int k  = (ct >> 2) * 32 + (ct & 3) * 8 + e;
    int p  = n >> 7, h = n & 127;
    const float* W = (p == 0) ? Wq : (p == 1 ? Wk : Wv);
    float v = W[(size_t)k * DH + h];
    if (p == 0) v *= 0.08838834764831845f * 1.4426950408889634f;
    WTc[gid] = bfbits(v);
}

// Fused QKV projection v5 (R14 passing version, best measured total):
// BM=64, BK=64, grid 256 (1 block/CU), B via global_load_lds, A reg-staged.
__global__ __launch_bounds__(512, 2) void qkv_kernel(const float* __restrict__ x,
                                                     const unsigned short* __restrict__ WTc,
                                                     unsigned short* __restrict__ Qb,
                                                     unsigned short* __restrict__ Kb,
                                                     unsigned short* __restrict__ VT){
    __shared__ unsigned short Bs[2][24576];   // 2 x 48KB
    __shared__ unsigned short As[2][4608];    // 2 x 9KB (64 rows x stride 72)

    const int tid  = threadIdx.x;
    const int lane = tid & 63;
    const int w    = tid >> 6;
    const int g = lane >> 4, c = lane & 15;
    const int m0 = blockIdx.x * 64;
    const int n0 = w * 48;

    const unsigned short* bsrc = WTc + (size_t)tid * 8;
    const int arow = tid >> 3, ac8 = tid & 7;
    const float* asrc = x + (size_t)(m0 + arow) * DC + ac8 * 8;

    f32x4 acc[4][3] = {};
    float4 av0, av1;

#pragma unroll
    for (int j = 0; j < 6; ++j)
        gload16(bsrc + j * 4096, &Bs[0][j * 4096 + tid * 8]);
    {
        av0 = *(const float4*)asrc; av1 = *(const float4*)(asrc + 4);
        i32x4 h8 = { (int)pbf2(av0.x, av0.y), (int)pbf2(av0.z, av0.w),
                     (int)pbf2(av1.x, av1.y), (int)pbf2(av1.z, av1.w) };
        *(i32x4*)(&As[0][arow * 72 + ac8 * 8]) = h8;
    }

    for (int t = 0; t < DC / 64; ++t){
        const int cur = t & 1;
        __syncthreads();
        if (t < DC / 64 - 1){
#pragma unroll
            for (int j = 0; j < 6; ++j)
                gload16(bsrc + (t + 1) * 24576 + j * 4096,
                        &Bs[cur ^ 1][j * 4096 + tid * 8]);
            av0 = *(const float4*)(asrc + (t + 1) * 64);
            av1 = *(const float4*)(asrc + (t + 1) * 64 + 4);
        }
#pragma unroll
        for (int kk = 0; kk < 2; ++kk){
            short8 af[4], bfr[3];
#pragma unroll
            for (int mf = 0; mf < 4; ++mf)
                af[mf] = *(const short8*)(&As[cur][(mf*16 + c) * 72 + kk*32 + g * 8]);
#pragma unroll
            for (int nf = 0; nf < 3; ++nf)
                bfr[nf] = *(const short8*)(&Bs[cur][kk*12288 + g * 3072 + (n0 + nf*16 + c) * 8]);
#pragma unroll
            for (int mf = 0; mf < 4; ++mf)
#pragma unroll
                for (int nf = 0; nf < 3; ++nf)
                    acc[mf][nf] = __builtin_amdgcn_mfma_f32_16x16x32_bf16(af[mf], bfr[nf], acc[mf][nf], 0, 0, 0);
        }
        if (t < DC / 64 - 1){
            i32x4 h8 = { (int)pbf2(av0.x, av0.y), (int)pbf2(av0.z, av0.w),
                         (int)pbf2(av1.x, av1.y), (int)pbf2(av1.z, av1.w) };
            *(i32x4*)(&As[cur ^ 1][arow * 72 + ac8 * 8]) = h8;
        }
    }

    const int bb = m0 >> 11;
    const int tb = m0 & 2047;
#pragma unroll
    for (int mf = 0; mf < 4; ++mf)
#pragma unroll
        for (int nf = 0; nf < 3; ++nf){
            const int n  = n0 + nf*16;
            const int p  = n >> 7;
            const int np = (n & 127) + c;
            const int row = m0 + mf*16 + 4*g;
            if (p < 2){
                unsigned short* O = (p == 0) ? Qb : Kb;
#pragma unroll
                for (int r = 0; r < 4; ++r)
                    O[(size_t)(row + r) * DH + np] = bfbits(acc[mf][nf][r]);
            } else {
                const int t0 = tb + mf*16 + 4*g;
                u16x4 v = { bfbits(acc[mf][nf][0]), bfbits(acc[mf][nf][1]),
                            bfbits(acc[mf][nf][2]), bfbits(acc[mf][nf][3]) };
                *(u16x4*)(VT + ((size_t)bb * DH + np) * DT + t0) = v;
            }
        }
}

// Causal flash attention v7 (R12/R14 passing version): 4 waves x 16 q-rows,
// kv-split-2, gload16 pre-swizzled-source double-buffer, one barrier/iter.
__global__ __launch_bounds__(256, 2) void attn_kernel(const unsigned short* __restrict__ Qb,
                                                      const unsigned short* __restrict__ Kb,
                                                      const unsigned short* __restrict__ VT,
                                                      unsigned short* __restrict__ OP,
                                                      float* __restrict__ ML){
    __shared__ unsigned char lds[2][32768];   // per buf: K 16KB @0, V 16KB @16384

    const int tid  = threadIdx.x;
    const int lane = tid & 63;
    const int w    = tid >> 6;
    const int g = lane >> 4, c = lane & 15;
    const int bi = blockIdx.x;
    const int b  = bi & 7;
    const int idx = bi >> 3;               // 0..63
    const int qt   = (idx < 32) ? (31 - idx) : (idx - 32);
    const int half = idx >> 5;
    const int q0 = qt * 64;
    const int qw = q0 + 16 * w;
    const int q  = qw + c;
    const int nt = qt + 1;
    const int h1 = (nt + 1) >> 1;
    const int kt0 = half ? h1 : 0;
    const int kt1 = half ? nt : h1;

    const unsigned short* Kbase = Kb + (size_t)b * DT * DH;
    const unsigned short* Vbase = VT + (size_t)b * DH * DT;

    short8 qf[4];
#pragma unroll
    for (int hc = 0; hc < 4; ++hc)
        qf[hc] = *(const short8*)(Qb + ((size_t)b*DT + qw + c) * DH + hc*32 + g*8);

    f32x4 acc[8] = {};
    float m = -1e30f, l = 0.f;

    if (kt0 < kt1){
        // ---- prologue: stage first tile into buf 0 ----
        {
            const int kv0 = kt0 * 64;
#pragma unroll
            for (int p = 0; p < 4; ++p){
                const int s = p*256 + tid;
                const int r = s >> 4, cbl = (s & 15) * 16;
                const int h = s >> 3, tbl = (s & 7) * 16;
                gload16(Kbase + (size_t)(kv0 + r) * DH + ((cbl ^ ((r & 7) << 4)) >> 1),
                        lds[0] + s*16);
                gload16(Vbase + (size_t)h * DT + kv0 + ((tbl ^ ((h & 7) << 4)) >> 1),
                        lds[0] + 16384 + s*16);
            }
        }

        for (int kt = kt0; kt < kt1; ++kt){
            const int cur = (kt - kt0) & 1;
            const int kv0c = kt * 64;
            __syncthreads();                      // buf[cur] staged (vmcnt drained)

            // ---- issue next tile direct-to-LDS (buf[cur^1]) ----
            if (kt + 1 < kt1){
                const int nv0 = kv0c + 64;
#pragma unroll
                for (int p = 0; p < 4; ++p){
                    const int s = p*256 + tid;
                    const int r = s >> 4, cbl = (s & 15) * 16;
                    const int h = s >> 3, tbl = (s & 7) * 16;
                    gload16(Kbase + (size_t)(nv0 + r) * DH + ((cbl ^ ((r & 7) << 4)) >> 1),
                            lds[cur ^ 1] + s*16);
                    gload16(Vbase + (size_t)h * DT + nv0 + ((tbl ^ ((h & 7) << 4)) >> 1),
                            lds[cur ^ 1] + 16384 + s*16);
                }
            }

            const unsigned char* kb = lds[cur];
            const unsigned char* vb = lds[cur] + 16384;

            // ---- QK^T from LDS K ----
            f32x4 s4[4] = {};
            short8 kf[4][4];
#pragma unroll
            for (int j = 0; j < 4; ++j){
                const int r = 16*j + c;
#pragma unroll
                for (int hc = 0; hc < 4; ++hc)
                    kf[j][hc] = *(const short8*)(kb + r*256 + ((hc*64 + g*16) ^ ((r & 7) << 4)));
            }
            __builtin_amdgcn_s_setprio(1);
#pragma unroll
            for (int hc = 0; hc < 4; ++hc)
#pragma unroll
                for (int j = 0; j < 4; ++j)
                    s4[j] = __builtin_amdgcn_mfma_f32_16x16x32_bf16(kf[j][hc], qf[hc], s4[j], 0,0,0);
            __builtin_amdgcn_s_setprio(0);

            // ---- causal mask (diagonal tile only) ----
            if (kt == nt - 1){
#pragma unroll
                for (int j = 0; j < 4; ++j){
                    const int o = kv0c + 16*j + 4*g;
#pragma unroll
                    for (int r = 0; r < 4; ++r)
                        if (o + r > q) s4[j][r] = -1e30f;
                }
            }

            // ---- online softmax with defer-max (T13) ----
            float tm = -1e30f;
#pragma unroll
            for (int j = 0; j < 4; ++j)
#pragma unroll
                for (int r = 0; r < 4; ++r) tm = fmaxf(tm, s4[j][r]);
            tm = fmaxf(tm, __shfl_xor(tm, 16));
            tm = fmaxf(tm, __shfl_xor(tm, 32));
            if (!__all(tm <= m + 8.f)){
                const float mn = fmaxf(m, tm);
                const float rs = exp2f(m - mn);
                l *= rs;
#pragma unroll
                for (int mt = 0; mt < 8; ++mt) acc[mt] *= rs;
                m = mn;
            }
            float p[4][4]; float ps = 0.f;
#pragma unroll
            for (int j = 0; j < 4; ++j)
#pragma unroll
                for (int r = 0; r < 4; ++r){
                    p[j][r] = exp2f(s4[j][r] - m);
                    ps += p[j][r];
                }
            ps += __shfl_xor(ps, 16);
            ps += __shfl_xor(ps, 32);
            l += ps;

            // ---- P -> B-fragment layout ----
            short8 pf0 = redist(pbf2(p[0][0], p[0][1]), pbf2(p[0][2], p[0][3]),
                                pbf2(p[1][0], p[1][1]), pbf2(p[1][2], p[1][3]), g, c);
            short8 pf1 = redist(pbf2(p[2][0], p[2][1]), pbf2(p[2][2], p[2][3]),
                                pbf2(p[3][0], p[3][1]), pbf2(p[3][2], p[3][3]), g, c);

            // ---- PV from LDS V ----
#pragma unroll
            for (int kk = 0; kk < 2; ++kk){
                short8 vf[8];
#pragma unroll
                for (int mt = 0; mt < 8; ++mt){
                    const int h = mt*16 + c;
                    vf[mt] = *(const short8*)(vb + h*128 + ((kk*64 + g*16) ^ ((h & 7) << 4)));
                }
                const short8 pf = kk ? pf1 : pf0;
                __builtin_amdgcn_s_setprio(1);
#pragma unroll
                for (int mt = 0; mt < 8; ++mt)
                    acc[mt] = __builtin_amdgcn_mfma_f32_16x16x32_bf16(vf[mt], pf, acc[mt], 0,0,0);
                __builtin_amdgcn_s_setprio(0);
            }
        }
    }

    // ---- store partial (bf16 O, f32 m/l) ----
    const size_t blk = ((size_t)(b * 32 + qt) * 2 + half);
    unsigned short* op = OP + blk * 8192;          // [64][128]
    const int row = 16*w + c;
#pragma unroll
    for (int mt = 0; mt < 8; ++mt){
        u16x4 h = { bfbits(acc[mt][0]), bfbits(acc[mt][1]),
                    bfbits(acc[mt][2]), bfbits(acc[mt][3]) };
        *(u16x4*)(op + row*128 + mt*16 + 4*g) = h;
    }
    if (g == 0){
        ML[(blk*64 + row)*2    ] = m;
        ML[(blk*64 + row)*2 + 1] = l;
    }
}

// 2-way merge. Grid 256 = (b, qt), 256 threads: r = tid>>2, colgroup = tid&3.
__global__ __launch_bounds__(256) void merge_kernel(const unsigned short* __restrict__ OP,
                                                    const float* __restrict__ ML,
                                                    float* __restrict__ out){
    const int tid = threadIdx.x;
    const int r  = tid >> 2;
    const int cq = (tid & 3) * 32;
    const int bi = blockIdx.x;
    const int b  = bi & 7;
    const int qt = bi >> 3;
    const size_t blk = (size_t)(b * 32 + qt) * 2;

    float ms[2], ls[2];
#pragma unroll
    for (int s = 0; s < 2; ++s){
        ms[s] = ML[((blk + s)*64 + r)*2    ];
        ls[s] = ML[((blk + s)*64 + r)*2 + 1];
    }
    const float M = fmaxf(ms[0], ms[1]);
    float sc[2]; float L = 0.f;
#pragma unroll
    for (int s = 0; s < 2; ++s){ sc[s] = exp2f(ms[s] - M); L += ls[s] * sc[s]; }
    const float inv = 1.0f / L;

    float* orow = out + ((size_t)(b * DT + qt*64 + r)) * DH + cq;
#pragma unroll
    for (int j = 0; j < 4; ++j){
        float o[8] = {};
#pragma unroll
        for (int s = 0; s < 2; ++s){
            short8 v = *(const short8*)(OP + (blk + s)*8192 + r*128 + cq + j*8);
#pragma unroll
            for (int e = 0; e < 8; ++e)
                o[e] += bf2f((unsigned short)v[e]) * sc[s];
        }
        f32x4 o0 = { o[0]*inv, o[1]*inv, o[2]*inv, o[3]*inv };
        f32x4 o1 = { o[4]*inv, o[5]*inv, o[6]*inv, o[7]*inv };
        *(f32x4*)(orow + j*8    ) = o0;
        *(f32x4*)(orow + j*8 + 4) = o1;
    }
}

extern "C" void kernel_launch(void* const* d_in, const int* in_sizes, int n_in,
                              void* d_out, int out_size, void* d_ws, size_t ws_size,
                              hipStream_t stream){
    const float* x  = (const float*)d_in[0];
    const float* Wq = (const float*)d_in[1];
    const float* Wk = (const float*)d_in[2];
    const float* Wv = (const float*)d_in[3];
    float* out = (float*)d_out;

    unsigned short* WTc = (unsigned short*)d_ws;         // [32][4][384][8] bf16
    unsigned short* Qb = WTc + 3 * DH * DC;              // [B*T][H]
    unsigned short* Kb = Qb + (size_t)DB * DT * DH;      // [B*T][H]
    unsigned short* VT = Kb + (size_t)DB * DT * DH;      // [B][H][T]
    unsigned short* OP = VT + (size_t)DB * DT * DH;      // [512][64][128] bf16
    float*          ML = (float*)(OP + (size_t)512 * 8192);  // [512][64][2] f32

    hipLaunchKernelGGL(prep_wt_kernel, dim3(1536), dim3(256), 0, stream, Wq, Wk, Wv, WTc);
    hipLaunchKernelGGL(qkv_kernel, dim3(256), dim3(512), 0, stream, x, WTc, Qb, Kb, VT);
    hipLaunchKernelGGL(attn_kernel, dim3(512), dim3(256), 0, stream, Qb, Kb, VT, OP, ML);
    hipLaunchKernelGGL(merge_kernel, dim3(256), dim3(256), 0, stream, OP, ML, out);
}

// Round 18
// 74.082 us; speedup vs baseline: 1.1051x; 1.0011x over previous
//
#include <hip/hip_runtime.h>
#include <hip/hip_bf16.h>

#define DB 8
#define DT 2048
#define DC 1024
#define DH 128

typedef __attribute__((ext_vector_type(8))) short short8;
typedef __attribute__((ext_vector_type(4))) float f32x4;
typedef __attribute__((ext_vector_type(4))) int i32x4;
typedef __attribute__((ext_vector_type(4))) unsigned short u16x4;

// round-to-nearest-even f32 -> bf16 bits
static __device__ __forceinline__ unsigned short bfbits(float x){
    union { float f; unsigned u; } a; a.f = x;
    unsigned u = a.u;
    unsigned r = u + 0x7fffu + ((u >> 16) & 1u);
    return (unsigned short)(r >> 16);
}
static __device__ __forceinline__ unsigned pbf2(float lo, float hi){
    return (unsigned)bfbits(lo) | ((unsigned)bfbits(hi) << 16);
}
static __device__ __forceinline__ float bf2f(unsigned short u){
    union { unsigned u; float f; } t; t.u = ((unsigned)u) << 16; return t.f;
}

// async 16B global -> LDS (direct, no VGPR round-trip)
static __device__ __forceinline__ void gload16(const void* g, void* l){
    __builtin_amdgcn_global_load_lds(
        (const __attribute__((address_space(1))) unsigned int*)g,
        (__attribute__((address_space(3))) unsigned int*)l, 16, 0, 0);
}

// Redistribute 32 kv-wide P slice into PV B-fragment layout. Verified R0..R17.
static __device__ __forceinline__ short8 redist(unsigned pk0, unsigned pk1,
                                                unsigned pk2, unsigned pk3,
                                                int g, int c){
    const int src0 = c + (((2*g    ) & 3) << 4);
    const int src1 = c + (((2*g + 1) & 3) << 4);
    const int sel  = g >> 1;
    unsigned a0 = __shfl(pk0, src0), a2 = __shfl(pk2, src0);
    unsigned b0 = __shfl(pk1, src0), b2 = __shfl(pk3, src0);
    unsigned c0 = __shfl(pk0, src1), c2 = __shfl(pk2, src1);
    unsigned d0 = __shfl(pk1, src1), d2 = __shfl(pk3, src1);
    i32x4 pw = { (int)(sel ? a2 : a0), (int)(sel ? b2 : b0),
                 (int)(sel ? c2 : c0), (int)(sel ? d2 : d0) };
    return __builtin_bit_cast(short8, pw);
}

// WTc[t][chunk][n][e] = W_p[k][h] bf16 (unchanged).
__global__ __launch_bounds__(256) void prep_wt_kernel(const float* __restrict__ Wq,
                                                      const float* __restrict__ Wk,
                                                      const float* __restrict__ Wv,
                                                      unsigned short* __restrict__ WTc){
    int gid = blockIdx.x * 256 + threadIdx.x;
    int e  = gid & 7;
    int F3 = gid >> 3;
    int n  = F3 % 384;
    int ct = F3 / 384;
    int k  = (ct >> 2) * 32 + (ct & 3) * 8 + e;
    int p  = n >> 7, h = n & 127;
    const float* W = (p == 0) ? Wq : (p == 1 ? Wk : Wv);
    float v = W[(size_t)k * DH + h];
    if (p == 0) v *= 0.08838834764831845f * 1.4426950408889634f;
    WTc[gid] = bfbits(v);
}

// Fused QKV projection v7: R14's BM=64/BK=64/grid-256 structure, plus
// per-block STAGGERED K-loop start (off = (bid*7)&15) so the 256 blocks do
// not request the same 48KB WTc window from L2 simultaneously (de-correlates
// the cross-CU convoy that kept qkv latency-bound). Accumulation order is a
// per-block-constant permutation -> deterministic across replays.
__global__ __launch_bounds__(512, 2) void qkv_kernel(const float* __restrict__ x,
                                                     const unsigned short* __restrict__ WTc,
                                                     unsigned short* __restrict__ Qb,
                                                     unsigned short* __restrict__ Kb,
                                                     unsigned short* __restrict__ VT){
    __shared__ unsigned short Bs[2][24576];   // 2 x 48KB
    __shared__ unsigned short As[2][4608];    // 2 x 9KB (64 rows x stride 72)

    const int tid  = threadIdx.x;
    const int lane = tid & 63;
    const int w    = tid >> 6;
    const int g = lane >> 4, c = lane & 15;
    const int m0 = blockIdx.x * 64;
    const int n0 = w * 48;
    const int off = (blockIdx.x * 7) & 15;    // staggered K start (16 tiles)

    const unsigned short* bsrc = WTc + (size_t)tid * 8;
    const int arow = tid >> 3, ac8 = tid & 7;
    const float* asrc = x + (size_t)(m0 + arow) * DC + ac8 * 8;

    f32x4 acc[4][3] = {};
    float4 av0, av1;

    // ---- prologue: stage tile `off` ----
#pragma unroll
    for (int j = 0; j < 6; ++j)
        gload16(bsrc + (size_t)off * 24576 + j * 4096, &Bs[0][j * 4096 + tid * 8]);
    {
        av0 = *(const float4*)(asrc + off * 64);
        av1 = *(const float4*)(asrc + off * 64 + 4);
        i32x4 h8 = { (int)pbf2(av0.x, av0.y), (int)pbf2(av0.z, av0.w),
                     (int)pbf2(av1.x, av1.y), (int)pbf2(av1.z, av1.w) };
        *(i32x4*)(&As[0][arow * 72 + ac8 * 8]) = h8;
    }

    for (int t = 0; t < DC / 64; ++t){
        const int cur = t & 1;
        __syncthreads();                 // buf[cur] staged (vmcnt drained)
        if (t < DC / 64 - 1){
            const int tn = (t + 1 + off) & 15;     // next tile (staggered)
#pragma unroll
            for (int j = 0; j < 6; ++j)
                gload16(bsrc + (size_t)tn * 24576 + j * 4096,
                        &Bs[cur ^ 1][j * 4096 + tid * 8]);
            av0 = *(const float4*)(asrc + tn * 64);
            av1 = *(const float4*)(asrc + tn * 64 + 4);
        }
#pragma unroll
        for (int kk = 0; kk < 2; ++kk){
            short8 af[4], bfr[3];
#pragma unroll
            for (int mf = 0; mf < 4; ++mf)
                af[mf] = *(const short8*)(&As[cur][(mf*16 + c) * 72 + kk*32 + g * 8]);
#pragma unroll
            for (int nf = 0; nf < 3; ++nf)
                bfr[nf] = *(const short8*)(&Bs[cur][kk*12288 + g * 3072 + (n0 + nf*16 + c) * 8]);
#pragma unroll
            for (int mf = 0; mf < 4; ++mf)
#pragma unroll
                for (int nf = 0; nf < 3; ++nf)
                    acc[mf][nf] = __builtin_amdgcn_mfma_f32_16x16x32_bf16(af[mf], bfr[nf], acc[mf][nf], 0, 0, 0);
        }
        if (t < DC / 64 - 1){
            i32x4 h8 = { (int)pbf2(av0.x, av0.y), (int)pbf2(av0.z, av0.w),
                         (int)pbf2(av1.x, av1.y), (int)pbf2(av1.z, av1.w) };
            *(i32x4*)(&As[cur ^ 1][arow * 72 + ac8 * 8]) = h8;
        }
    }

    const int bb = m0 >> 11;
    const int tb = m0 & 2047;
#pragma unroll
    for (int mf = 0; mf < 4; ++mf)
#pragma unroll
        for (int nf = 0; nf < 3; ++nf){
            const int n  = n0 + nf*16;
            const int p  = n >> 7;
            const int np = (n & 127) + c;
            const int row = m0 + mf*16 + 4*g;
            if (p < 2){
                unsigned short* O = (p == 0) ? Qb : Kb;
#pragma unroll
                for (int r = 0; r < 4; ++r)
                    O[(size_t)(row + r) * DH + np] = bfbits(acc[mf][nf][r]);
            } else {
                const int t0 = tb + mf*16 + 4*g;
                u16x4 v = { bfbits(acc[mf][nf][0]), bfbits(acc[mf][nf][1]),
                            bfbits(acc[mf][nf][2]), bfbits(acc[mf][nf][3]) };
                *(u16x4*)(VT + ((size_t)bb * DH + np) * DT + t0) = v;
            }
        }
}

// Causal flash attention v7 (R12/R14/R17 passing version): 4 waves x 16 q-rows,
// kv-split-2, gload16 pre-swizzled-source double-buffer, one barrier/iter.
__global__ __launch_bounds__(256, 2) void attn_kernel(const unsigned short* __restrict__ Qb,
                                                      const unsigned short* __restrict__ Kb,
                                                      const unsigned short* __restrict__ VT,
                                                      unsigned short* __restrict__ OP,
                                                      float* __restrict__ ML){
    __shared__ unsigned char lds[2][32768];   // per buf: K 16KB @0, V 16KB @16384

    const int tid  = threadIdx.x;
    const int lane = tid & 63;
    const int w    = tid >> 6;
    const int g = lane >> 4, c = lane & 15;
    const int bi = blockIdx.x;
    const int b  = bi & 7;
    const int idx = bi >> 3;               // 0..63
    const int qt   = (idx < 32) ? (31 - idx) : (idx - 32);
    const int half = idx >> 5;
    const int q0 = qt * 64;
    const int qw = q0 + 16 * w;
    const int q  = qw + c;
    const int nt = qt + 1;
    const int h1 = (nt + 1) >> 1;
    const int kt0 = half ? h1 : 0;
    const int kt1 = half ? nt : h1;

    const unsigned short* Kbase = Kb + (size_t)b * DT * DH;
    const unsigned short* Vbase = VT + (size_t)b * DH * DT;

    short8 qf[4];
#pragma unroll
    for (int hc = 0; hc < 4; ++hc)
        qf[hc] = *(const short8*)(Qb + ((size_t)b*DT + qw + c) * DH + hc*32 + g*8);

    f32x4 acc[8] = {};
    float m = -1e30f, l = 0.f;

    if (kt0 < kt1){
        // ---- prologue: stage first tile into buf 0 ----
        {
            const int kv0 = kt0 * 64;
#pragma unroll
            for (int p = 0; p < 4; ++p){
                const int s = p*256 + tid;
                const int r = s >> 4, cbl = (s & 15) * 16;
                const int h = s >> 3, tbl = (s & 7) * 16;
                gload16(Kbase + (size_t)(kv0 + r) * DH + ((cbl ^ ((r & 7) << 4)) >> 1),
                        lds[0] + s*16);
                gload16(Vbase + (size_t)h * DT + kv0 + ((tbl ^ ((h & 7) << 4)) >> 1),
                        lds[0] + 16384 + s*16);
            }
        }

        for (int kt = kt0; kt < kt1; ++kt){
            const int cur = (kt - kt0) & 1;
            const int kv0c = kt * 64;
            __syncthreads();                      // buf[cur] staged (vmcnt drained)

            // ---- issue next tile direct-to-LDS (buf[cur^1]) ----
            if (kt + 1 < kt1){
                const int nv0 = kv0c + 64;
#pragma unroll
                for (int p = 0; p < 4; ++p){
                    const int s = p*256 + tid;
                    const int r = s >> 4, cbl = (s & 15) * 16;
                    const int h = s >> 3, tbl = (s & 7) * 16;
                    gload16(Kbase + (size_t)(nv0 + r) * DH + ((cbl ^ ((r & 7) << 4)) >> 1),
                            lds[cur ^ 1] + s*16);
                    gload16(Vbase + (size_t)h * DT + nv0 + ((tbl ^ ((h & 7) << 4)) >> 1),
                            lds[cur ^ 1] + 16384 + s*16);
                }
            }

            const unsigned char* kb = lds[cur];
            const unsigned char* vb = lds[cur] + 16384;

            // ---- QK^T from LDS K ----
            f32x4 s4[4] = {};
            short8 kf[4][4];
#pragma unroll
            for (int j = 0; j < 4; ++j){
                const int r = 16*j + c;
#pragma unroll
                for (int hc = 0; hc < 4; ++hc)
                    kf[j][hc] = *(const short8*)(kb + r*256 + ((hc*64 + g*16) ^ ((r & 7) << 4)));
            }
            __builtin_amdgcn_s_setprio(1);
#pragma unroll
            for (int hc = 0; hc < 4; ++hc)
#pragma unroll
                for (int j = 0; j < 4; ++j)
                    s4[j] = __builtin_amdgcn_mfma_f32_16x16x32_bf16(kf[j][hc], qf[hc], s4[j], 0,0,0);
            __builtin_amdgcn_s_setprio(0);

            // ---- causal mask (diagonal tile only) ----
            if (kt == nt - 1){
#pragma unroll
                for (int j = 0; j < 4; ++j){
                    const int o = kv0c + 16*j + 4*g;
#pragma unroll
                    for (int r = 0; r < 4; ++r)
                        if (o + r > q) s4[j][r] = -1e30f;
                }
            }

            // ---- online softmax with defer-max (T13) ----
            float tm = -1e30f;
#pragma unroll
            for (int j = 0; j < 4; ++j)
#pragma unroll
                for (int r = 0; r < 4; ++r) tm = fmaxf(tm, s4[j][r]);
            tm = fmaxf(tm, __shfl_xor(tm, 16));
            tm = fmaxf(tm, __shfl_xor(tm, 32));
            if (!__all(tm <= m + 8.f)){
                const float mn = fmaxf(m, tm);
                const float rs = exp2f(m - mn);
                l *= rs;
#pragma unroll
                for (int mt = 0; mt < 8; ++mt) acc[mt] *= rs;
                m = mn;
            }
            float p[4][4]; float ps = 0.f;
#pragma unroll
            for (int j = 0; j < 4; ++j)
#pragma unroll
                for (int r = 0; r < 4; ++r){
                    p[j][r] = exp2f(s4[j][r] - m);
                    ps += p[j][r];
                }
            ps += __shfl_xor(ps, 16);
            ps += __shfl_xor(ps, 32);
            l += ps;

            // ---- P -> B-fragment layout ----
            short8 pf0 = redist(pbf2(p[0][0], p[0][1]), pbf2(p[0][2], p[0][3]),
                                pbf2(p[1][0], p[1][1]), pbf2(p[1][2], p[1][3]), g, c);
            short8 pf1 = redist(pbf2(p[2][0], p[2][1]), pbf2(p[2][2], p[2][3]),
                                pbf2(p[3][0], p[3][1]), pbf2(p[3][2], p[3][3]), g, c);

            // ---- PV from LDS V ----
#pragma unroll
            for (int kk = 0; kk < 2; ++kk){
                short8 vf[8];
#pragma unroll
                for (int mt = 0; mt < 8; ++mt){
                    const int h = mt*16 + c;
                    vf[mt] = *(const short8*)(vb + h*128 + ((kk*64 + g*16) ^ ((h & 7) << 4)));
                }
                const short8 pf = kk ? pf1 : pf0;
                __builtin_amdgcn_s_setprio(1);
#pragma unroll
                for (int mt = 0; mt < 8; ++mt)
                    acc[mt] = __builtin_amdgcn_mfma_f32_16x16x32_bf16(vf[mt], pf, acc[mt], 0,0,0);
                __builtin_amdgcn_s_setprio(0);
            }
        }
    }

    // ---- store partial (bf16 O, f32 m/l) ----
    const size_t blk = ((size_t)(b * 32 + qt) * 2 + half);
    unsigned short* op = OP + blk * 8192;          // [64][128]
    const int row = 16*w + c;
#pragma unroll
    for (int mt = 0; mt < 8; ++mt){
        u16x4 h = { bfbits(acc[mt][0]), bfbits(acc[mt][1]),
                    bfbits(acc[mt][2]), bfbits(acc[mt][3]) };
        *(u16x4*)(op + row*128 + mt*16 + 4*g) = h;
    }
    if (g == 0){
        ML[(blk*64 + row)*2    ] = m;
        ML[(blk*64 + row)*2 + 1] = l;
    }
}

// 2-way merge. Grid 256 = (b, qt), 256 threads: r = tid>>2, colgroup = tid&3.
__global__ __launch_bounds__(256) void merge_kernel(const unsigned short* __restrict__ OP,
                                                    const float* __restrict__ ML,
                                                    float* __restrict__ out){
    const int tid = threadIdx.x;
    const int r  = tid >> 2;
    const int cq = (tid & 3) * 32;
    const int bi = blockIdx.x;
    const int b  = bi & 7;
    const int qt = bi >> 3;
    const size_t blk = (size_t)(b * 32 + qt) * 2;

    float ms[2], ls[2];
#pragma unroll
    for (int s = 0; s < 2; ++s){
        ms[s] = ML[((blk + s)*64 + r)*2    ];
        ls[s] = ML[((blk + s)*64 + r)*2 + 1];
    }
    const float M = fmaxf(ms[0], ms[1]);
    float sc[2]; float L = 0.f;
#pragma unroll
    for (int s = 0; s < 2; ++s){ sc[s] = exp2f(ms[s] - M); L += ls[s] * sc[s]; }
    const float inv = 1.0f / L;

    float* orow = out + ((size_t)(b * DT + qt*64 + r)) * DH + cq;
#pragma unroll
    for (int j = 0; j < 4; ++j){
        float o[8] = {};
#pragma unroll
        for (int s = 0; s < 2; ++s){
            short8 v = *(const short8*)(OP + (blk + s)*8192 + r*128 + cq + j*8);
#pragma unroll
            for (int e = 0; e < 8; ++e)
                o[e] += bf2f((unsigned short)v[e]) * sc[s];
        }
        f32x4 o0 = { o[0]*inv, o[1]*inv, o[2]*inv, o[3]*inv };
        f32x4 o1 = { o[4]*inv, o[5]*inv, o[6]*inv, o[7]*inv };
        *(f32x4*)(orow + j*8    ) = o0;
        *(f32x4*)(orow + j*8 + 4) = o1;
    }
}

extern "C" void kernel_launch(void* const* d_in, const int* in_sizes, int n_in,
                              void* d_out, int out_size, void* d_ws, size_t ws_size,
                              hipStream_t stream){
    const float* x  = (const float*)d_in[0];
    const float* Wq = (const float*)d_in[1];
    const float* Wk = (const float*)d_in[2];
    const float* Wv = (const float*)d_in[3];
    float* out = (float*)d_out;

    unsigned short* WTc = (unsigned short*)d_ws;         // [32][4][384][8] bf16
    unsigned short* Qb = WTc + 3 * DH * DC;              // [B*T][H]
    unsigned short* Kb = Qb + (size_t)DB * DT * DH;      // [B*T][H]
    unsigned short* VT = Kb + (size_t)DB * DT * DH;      // [B][H][T]
    unsigned short* OP = VT + (size_t)DB * DT * DH;      // [512][64][128] bf16
    float*          ML = (float*)(OP + (size_t)512 * 8192);  // [512][64][2] f32

    hipLaunchKernelGGL(prep_wt_kernel, dim3(1536), dim3(256), 0, stream, Wq, Wk, Wv, WTc);
    hipLaunchKernelGGL(qkv_kernel, dim3(256), dim3(512), 0, stream, x, WTc, Qb, Kb, VT);
    hipLaunchKernelGGL(attn_kernel, dim3(512), dim3(256), 0, stream, Qb, Kb, VT, OP, ML);
    hipLaunchKernelGGL(merge_kernel, dim3(256), dim3(256), 0, stream, OP, ML, out);
}

// Round 20
// 73.568 us; speedup vs baseline: 1.1128x; 1.0070x over previous
//
#include <hip/hip_runtime.h>
#include <hip/hip_bf16.h>

#define DB 8
#define DT 2048
#define DC 1024
#define DH 128

typedef __attribute__((ext_vector_type(8))) short short8;
typedef __attribute__((ext_vector_type(4))) float f32x4;
typedef __attribute__((ext_vector_type(4))) int i32x4;
typedef __attribute__((ext_vector_type(4))) unsigned short u16x4;

// f32 -> bf16 via compiler-native cast (RNE, same rounding as the prior
// hand-rolled version; fewer VALU ops). Bits extracted with memcpy because
// __hip_bfloat16 is not trivially copyable on this ROCm.
static __device__ __forceinline__ unsigned short bfbits(float x){
    __hip_bfloat16 h = __float2bfloat16(x);
    unsigned short u;
    __builtin_memcpy(&u, &h, 2);
    return u;
}
static __device__ __forceinline__ unsigned pbf2(float lo, float hi){
    return (unsigned)bfbits(lo) | ((unsigned)bfbits(hi) << 16);
}
static __device__ __forceinline__ float bf2f(unsigned short u){
    union { unsigned u; float f; } t; t.u = ((unsigned)u) << 16; return t.f;
}

// async 16B global -> LDS (direct, no VGPR round-trip)
static __device__ __forceinline__ void gload16(const void* g, void* l){
    __builtin_amdgcn_global_load_lds(
        (const __attribute__((address_space(1))) unsigned int*)g,
        (__attribute__((address_space(3))) unsigned int*)l, 16, 0, 0);
}

// Redistribute 32 kv-wide P slice into PV B-fragment layout. Verified R0..R18.
static __device__ __forceinline__ short8 redist(unsigned pk0, unsigned pk1,
                                                unsigned pk2, unsigned pk3,
                                                int g, int c){
    const int src0 = c + (((2*g    ) & 3) << 4);
    const int src1 = c + (((2*g + 1) & 3) << 4);
    const int sel  = g >> 1;
    unsigned a0 = __shfl(pk0, src0), a2 = __shfl(pk2, src0);
    unsigned b0 = __shfl(pk1, src0), b2 = __shfl(pk3, src0);
    unsigned c0 = __shfl(pk0, src1), c2 = __shfl(pk2, src1);
    unsigned d0 = __shfl(pk1, src1), d2 = __shfl(pk3, src1);
    i32x4 pw = { (int)(sel ? a2 : a0), (int)(sel ? b2 : b0),
                 (int)(sel ? c2 : c0), (int)(sel ? d2 : d0) };
    return __builtin_bit_cast(short8, pw);
}

// WTc[t][chunk][n][e] = W_p[k][h] bf16 (unchanged).
__global__ __launch_bounds__(256) void prep_wt_kernel(const float* __restrict__ Wq,
                                                      const float* __restrict__ Wk,
                                                      const float* __restrict__ Wv,
                                                      unsigned short* __restrict__ WTc){
    int gid = blockIdx.x * 256 + threadIdx.x;
    int e  = gid & 7;
    int F3 = gid >> 3;
    int n  = F3 % 384;
    int ct = F3 / 384;
    int k  = (ct >> 2) * 32 + (ct & 3) * 8 + e;
    int p  = n >> 7, h = n & 127;
    const float* W = (p == 0) ? Wq : (p == 1 ? Wk : Wv);
    float v = W[(size_t)k * DH + h];
    if (p == 0) v *= 0.08838834764831845f * 1.4426950408889634f;
    WTc[gid] = bfbits(v);
}

// Fused QKV projection v7 (R18 passing config): BM=64/BK=64/grid-256,
// staggered K start, B via global_load_lds, A reg-staged with native cvt.
__global__ __launch_bounds__(512, 2) void qkv_kernel(const float* __restrict__ x,
                                                     const unsigned short* __restrict__ WTc,
                                                     unsigned short* __restrict__ Qb,
                                                     unsigned short* __restrict__ Kb,
                                                     unsigned short* __restrict__ VT){
    __shared__ unsigned short Bs[2][24576];   // 2 x 48KB
    __shared__ unsigned short As[2][4608];    // 2 x 9KB (64 rows x stride 72)

    const int tid  = threadIdx.x;
    const int lane = tid & 63;
    const int w    = tid >> 6;
    const int g = lane >> 4, c = lane & 15;
    const int m0 = blockIdx.x * 64;
    const int n0 = w * 48;
    const int off = (blockIdx.x * 7) & 15;    // staggered K start (16 tiles)

    const unsigned short* bsrc = WTc + (size_t)tid * 8;
    const int arow = tid >> 3, ac8 = tid & 7;
    const float* asrc = x + (size_t)(m0 + arow) * DC + ac8 * 8;

    f32x4 acc[4][3] = {};
    float4 av0, av1;

    // ---- prologue: stage tile `off` ----
#pragma unroll
    for (int j = 0; j < 6; ++j)
        gload16(bsrc + (size_t)off * 24576 + j * 4096, &Bs[0][j * 4096 + tid * 8]);
    {
        av0 = *(const float4*)(asrc + off * 64);
        av1 = *(const float4*)(asrc + off * 64 + 4);
        i32x4 h8 = { (int)pbf2(av0.x, av0.y), (int)pbf2(av0.z, av0.w),
                     (int)pbf2(av1.x, av1.y), (int)pbf2(av1.z, av1.w) };
        *(i32x4*)(&As[0][arow * 72 + ac8 * 8]) = h8;
    }

    for (int t = 0; t < DC / 64; ++t){
        const int cur = t & 1;
        __syncthreads();                 // buf[cur] staged (vmcnt drained)
        if (t < DC / 64 - 1){
            const int tn = (t + 1 + off) & 15;     // next tile (staggered)
#pragma unroll
            for (int j = 0; j < 6; ++j)
                gload16(bsrc + (size_t)tn * 24576 + j * 4096,
                        &Bs[cur ^ 1][j * 4096 + tid * 8]);
            av0 = *(const float4*)(asrc + tn * 64);
            av1 = *(const float4*)(asrc + tn * 64 + 4);
        }
#pragma unroll
        for (int kk = 0; kk < 2; ++kk){
            short8 af[4], bfr[3];
#pragma unroll
            for (int mf = 0; mf < 4; ++mf)
                af[mf] = *(const short8*)(&As[cur][(mf*16 + c) * 72 + kk*32 + g * 8]);
#pragma unroll
            for (int nf = 0; nf < 3; ++nf)
                bfr[nf] = *(const short8*)(&Bs[cur][kk*12288 + g * 3072 + (n0 + nf*16 + c) * 8]);
#pragma unroll
            for (int mf = 0; mf < 4; ++mf)
#pragma unroll
                for (int nf = 0; nf < 3; ++nf)
                    acc[mf][nf] = __builtin_amdgcn_mfma_f32_16x16x32_bf16(af[mf], bfr[nf], acc[mf][nf], 0, 0, 0);
        }
        if (t < DC / 64 - 1){
            i32x4 h8 = { (int)pbf2(av0.x, av0.y), (int)pbf2(av0.z, av0.w),
                         (int)pbf2(av1.x, av1.y), (int)pbf2(av1.z, av1.w) };
            *(i32x4*)(&As[cur ^ 1][arow * 72 + ac8 * 8]) = h8;
        }
    }

    const int bb = m0 >> 11;
    const int tb = m0 & 2047;
#pragma unroll
    for (int mf = 0; mf < 4; ++mf)
#pragma unroll
        for (int nf = 0; nf < 3; ++nf){
            const int n  = n0 + nf*16;
            const int p  = n >> 7;
            const int np = (n & 127) + c;
            const int row = m0 + mf*16 + 4*g;
            if (p < 2){
                unsigned short* O = (p == 0) ? Qb : Kb;
#pragma unroll
                for (int r = 0; r < 4; ++r)
                    O[(size_t)(row + r) * DH + np] = bfbits(acc[mf][nf][r]);
            } else {
                const int t0 = tb + mf*16 + 4*g;
                u16x4 v = { bfbits(acc[mf][nf][0]), bfbits(acc[mf][nf][1]),
                            bfbits(acc[mf][nf][2]), bfbits(acc[mf][nf][3]) };
                *(u16x4*)(VT + ((size_t)bb * DH + np) * DT + t0) = v;
            }
        }
}

// Causal flash attention v7 (R12/R14/R17/R18 passing version).
__global__ __launch_bounds__(256, 2) void attn_kernel(const unsigned short* __restrict__ Qb,
                                                      const unsigned short* __restrict__ Kb,
                                                      const unsigned short* __restrict__ VT,
                                                      unsigned short* __restrict__ OP,
                                                      float* __restrict__ ML){
    __shared__ unsigned char lds[2][32768];   // per buf: K 16KB @0, V 16KB @16384

    const int tid  = threadIdx.x;
    const int lane = tid & 63;
    const int w    = tid >> 6;
    const int g = lane >> 4, c = lane & 15;
    const int bi = blockIdx.x;
    const int b  = bi & 7;
    const int idx = bi >> 3;               // 0..63
    const int qt   = (idx < 32) ? (31 - idx) : (idx - 32);
    const int half = idx >> 5;
    const int q0 = qt * 64;
    const int qw = q0 + 16 * w;
    const int q  = qw + c;
    const int nt = qt + 1;
    const int h1 = (nt + 1) >> 1;
    const int kt0 = half ? h1 : 0;
    const int kt1 = half ? nt : h1;

    const unsigned short* Kbase = Kb + (size_t)b * DT * DH;
    const unsigned short* Vbase = VT + (size_t)b * DH * DT;

    short8 qf[4];
#pragma unroll
    for (int hc = 0; hc < 4; ++hc)
        qf[hc] = *(const short8*)(Qb + ((size_t)b*DT + qw + c) * DH + hc*32 + g*8);

    f32x4 acc[8] = {};
    float m = -1e30f, l = 0.f;

    if (kt0 < kt1){
        // ---- prologue: stage first tile into buf 0 ----
        {
            const int kv0 = kt0 * 64;
#pragma unroll
            for (int p = 0; p < 4; ++p){
                const int s = p*256 + tid;
                const int r = s >> 4, cbl = (s & 15) * 16;
                const int h = s >> 3, tbl = (s & 7) * 16;
                gload16(Kbase + (size_t)(kv0 + r) * DH + ((cbl ^ ((r & 7) << 4)) >> 1),
                        lds[0] + s*16);
                gload16(Vbase + (size_t)h * DT + kv0 + ((tbl ^ ((h & 7) << 4)) >> 1),
                        lds[0] + 16384 + s*16);
            }
        }

        for (int kt = kt0; kt < kt1; ++kt){
            const int cur = (kt - kt0) & 1;
            const int kv0c = kt * 64;
            __syncthreads();                      // buf[cur] staged (vmcnt drained)

            // ---- issue next tile direct-to-LDS (buf[cur^1]) ----
            if (kt + 1 < kt1){
                const int nv0 = kv0c + 64;
#pragma unroll
                for (int p = 0; p < 4; ++p){
                    const int s = p*256 + tid;
                    const int r = s >> 4, cbl = (s & 15) * 16;
                    const int h = s >> 3, tbl = (s & 7) * 16;
                    gload16(Kbase + (size_t)(nv0 + r) * DH + ((cbl ^ ((r & 7) << 4)) >> 1),
                            lds[cur ^ 1] + s*16);
                    gload16(Vbase + (size_t)h * DT + nv0 + ((tbl ^ ((h & 7) << 4)) >> 1),
                            lds[cur ^ 1] + 16384 + s*16);
                }
            }

            const unsigned char* kb = lds[cur];
            const unsigned char* vb = lds[cur] + 16384;

            // ---- QK^T from LDS K ----
            f32x4 s4[4] = {};
            short8 kf[4][4];
#pragma unroll
            for (int j = 0; j < 4; ++j){
                const int r = 16*j + c;
#pragma unroll
                for (int hc = 0; hc < 4; ++hc)
                    kf[j][hc] = *(const short8*)(kb + r*256 + ((hc*64 + g*16) ^ ((r & 7) << 4)));
            }
            __builtin_amdgcn_s_setprio(1);
#pragma unroll
            for (int hc = 0; hc < 4; ++hc)
#pragma unroll
                for (int j = 0; j < 4; ++j)
                    s4[j] = __builtin_amdgcn_mfma_f32_16x16x32_bf16(kf[j][hc], qf[hc], s4[j], 0,0,0);
            __builtin_amdgcn_s_setprio(0);

            // ---- causal mask (diagonal tile only) ----
            if (kt == nt - 1){
#pragma unroll
                for (int j = 0; j < 4; ++j){
                    const int o = kv0c + 16*j + 4*g;
#pragma unroll
                    for (int r = 0; r < 4; ++r)
                        if (o + r > q) s4[j][r] = -1e30f;
                }
            }

            // ---- online softmax with defer-max (T13) ----
            float tm = -1e30f;
#pragma unroll
            for (int j = 0; j < 4; ++j)
#pragma unroll
                for (int r = 0; r < 4; ++r) tm = fmaxf(tm, s4[j][r]);
            tm = fmaxf(tm, __shfl_xor(tm, 16));
            tm = fmaxf(tm, __shfl_xor(tm, 32));
            if (!__all(tm <= m + 8.f)){
                const float mn = fmaxf(m, tm);
                const float rs = exp2f(m - mn);
                l *= rs;
#pragma unroll
                for (int mt = 0; mt < 8; ++mt) acc[mt] *= rs;
                m = mn;
            }
            float p[4][4]; float ps = 0.f;
#pragma unroll
            for (int j = 0; j < 4; ++j)
#pragma unroll
                for (int r = 0; r < 4; ++r){
                    p[j][r] = exp2f(s4[j][r] - m);
                    ps += p[j][r];
                }
            ps += __shfl_xor(ps, 16);
            ps += __shfl_xor(ps, 32);
            l += ps;

            // ---- P -> B-fragment layout ----
            short8 pf0 = redist(pbf2(p[0][0], p[0][1]), pbf2(p[0][2], p[0][3]),
                                pbf2(p[1][0], p[1][1]), pbf2(p[1][2], p[1][3]), g, c);
            short8 pf1 = redist(pbf2(p[2][0], p[2][1]), pbf2(p[2][2], p[2][3]),
                                pbf2(p[3][0], p[3][1]), pbf2(p[3][2], p[3][3]), g, c);

            // ---- PV from LDS V ----
#pragma unroll
            for (int kk = 0; kk < 2; ++kk){
                short8 vf[8];
#pragma unroll
                for (int mt = 0; mt < 8; ++mt){
                    const int h = mt*16 + c;
                    vf[mt] = *(const short8*)(vb + h*128 + ((kk*64 + g*16) ^ ((h & 7) << 4)));
                }
                const short8 pf = kk ? pf1 : pf0;
                __builtin_amdgcn_s_setprio(1);
#pragma unroll
                for (int mt = 0; mt < 8; ++mt)
                    acc[mt] = __builtin_amdgcn_mfma_f32_16x16x32_bf16(vf[mt], pf, acc[mt], 0,0,0);
                __builtin_amdgcn_s_setprio(0);
            }
        }
    }

    // ---- store partial (bf16 O, f32 m/l) ----
    const size_t blk = ((size_t)(b * 32 + qt) * 2 + half);
    unsigned short* op = OP + blk * 8192;          // [64][128]
    const int row = 16*w + c;
#pragma unroll
    for (int mt = 0; mt < 8; ++mt){
        u16x4 h = { bfbits(acc[mt][0]), bfbits(acc[mt][1]),
                    bfbits(acc[mt][2]), bfbits(acc[mt][3]) };
        *(u16x4*)(op + row*128 + mt*16 + 4*g) = h;
    }
    if (g == 0){
        ML[(blk*64 + row)*2    ] = m;
        ML[(blk*64 + row)*2 + 1] = l;
    }
}

// 2-way merge. Grid 256 = (b, qt), 256 threads: r = tid>>2, colgroup = tid&3.
__global__ __launch_bounds__(256) void merge_kernel(const unsigned short* __restrict__ OP,
                                                    const float* __restrict__ ML,
                                                    float* __restrict__ out){
    const int tid = threadIdx.x;
    const int r  = tid >> 2;
    const int cq = (tid & 3) * 32;
    const int bi = blockIdx.x;
    const int b  = bi & 7;
    const int qt = bi >> 3;
    const size_t blk = (size_t)(b * 32 + qt) * 2;

    float ms[2], ls[2];
#pragma unroll
    for (int s = 0; s < 2; ++s){
        ms[s] = ML[((blk + s)*64 + r)*2    ];
        ls[s] = ML[((blk + s)*64 + r)*2 + 1];
    }
    const float M = fmaxf(ms[0], ms[1]);
    float sc[2]; float L = 0.f;
#pragma unroll
    for (int s = 0; s < 2; ++s){ sc[s] = exp2f(ms[s] - M); L += ls[s] * sc[s]; }
    const float inv = 1.0f / L;

    float* orow = out + ((size_t)(b * DT + qt*64 + r)) * DH + cq;
#pragma unroll
    for (int j = 0; j < 4; ++j){
        float o[8] = {};
#pragma unroll
        for (int s = 0; s < 2; ++s){
            short8 v = *(const short8*)(OP + (blk + s)*8192 + r*128 + cq + j*8);
#pragma unroll
            for (int e = 0; e < 8; ++e)
                o[e] += bf2f((unsigned short)v[e]) * sc[s];
        }
        f32x4 o0 = { o[0]*inv, o[1]*inv, o[2]*inv, o[3]*inv };
        f32x4 o1 = { o[4]*inv, o[5]*inv, o[6]*inv, o[7]*inv };
        *(f32x4*)(orow + j*8    ) = o0;
        *(f32x4*)(orow + j*8 + 4) = o1;
    }
}

extern "C" void kernel_launch(void* const* d_in, const int* in_sizes, int n_in,
                              void* d_out, int out_size, void* d_ws, size_t ws_size,
                              hipStream_t stream){
    const float* x  = (const float*)d_in[0];
    const float* Wq = (const float*)d_in[1];
    const float* Wk = (const float*)d_in[2];
    const float* Wv = (const float*)d_in[3];
    float* out = (float*)d_out;

    unsigned short* WTc = (unsigned short*)d_ws;         // [32][4][384][8] bf16
    unsigned short* Qb = WTc + 3 * DH * DC;              // [B*T][H]
    unsigned short* Kb = Qb + (size_t)DB * DT * DH;      // [B*T][H]
    unsigned short* VT = Kb + (size_t)DB * DT * DH;      // [B][H][T]
    unsigned short* OP = VT + (size_t)DB * DT * DH;      // [512][64][128] bf16
    float*          ML = (float*)(OP + (size_t)512 * 8192);  // [512][64][2] f32

    hipLaunchKernelGGL(prep_wt_kernel, dim3(1536), dim3(256), 0, stream, Wq, Wk, Wv, WTc);
    hipLaunchKernelGGL(qkv_kernel, dim3(256), dim3(512), 0, stream, x, WTc, Qb, Kb, VT);
    hipLaunchKernelGGL(attn_kernel, dim3(512), dim3(256), 0, stream, Qb, Kb, VT, OP, ML);
    hipLaunchKernelGGL(merge_kernel, dim3(256), dim3(256), 0, stream, OP, ML, out);
}